// Round 1
// baseline (137.423 us; speedup 1.0000x reference)
//
#include <hip/hip_runtime.h>
#include <hip/hip_bf16.h>

// DisjointDense: out[b] = x[b] @ W[sel[b]] + Bw[sel[b]]
// B=4096, D_IN=256, D_OUT=256, N_DISJOINT=64, all fp32.
//
// Strategy: bucket rows by selected block d, then one small GEMM per bucket
// so each W[d] (256 KB) is read ~4x total instead of once per row.

#define NBLK 64
#define BCAP 1024            // bucket capacity (avg count is 64; 1024 is untouchable for uniform random)
#define ROWS 16              // rows per workgroup tile
#define WPB  4               // workgroups per bucket

__global__ __launch_bounds__(256) void dd_bucketize(
    const float* __restrict__ onehot,   // [4096, 64]
    int* __restrict__ counts,           // [64]
    int* __restrict__ buckets)          // [64, BCAP]
{
    const int wave = threadIdx.x >> 6;
    const int lane = threadIdx.x & 63;
    const int b = blockIdx.x * 4 + wave;          // 1024 blocks * 4 waves = 4096 rows
    const float v = onehot[b * NBLK + lane];
    const unsigned long long m = __ballot(v > 0.5f);
    const int d = __ffsll(m) - 1;
    if (lane == 0) {
        int slot = atomicAdd(&counts[d], 1);
        if (slot < BCAP) buckets[d * BCAP + slot] = b;
    }
}

__global__ __launch_bounds__(256) void dd_compute(
    const float* __restrict__ x,        // [4096, 256]
    const float* __restrict__ W,        // [64, 256, 256]  (d, in, out)
    const float* __restrict__ Bw,       // [64, 256]
    const int* __restrict__ counts,     // [64]
    const int* __restrict__ buckets,    // [64, BCAP]
    float* __restrict__ out)            // [4096, 256]
{
    __shared__ float xs[ROWS][256];     // staged x rows (fp32, 16 KB)
    __shared__ int  rid[ROWS];

    const int d   = blockIdx.x >> 2;    // bucket id (WPB=4)
    const int sub = blockIdx.x & 3;
    const int tid = threadIdx.x;        // output column o
    const int cnt = counts[d];

    const float* wp = W + (size_t)d * (256 * 256) + tid;   // column o of W[d]; stride 256 over k
    const float  bw = Bw[d * 256 + tid];

    for (int base = sub * ROWS; base < cnt; base += WPB * ROWS) {
        const int nr = min(ROWS, cnt - base);

        // stage nr x-rows into LDS (coalesced: thread tid loads element tid of each row)
        for (int r = 0; r < nr; ++r) {
            const int b = buckets[d * BCAP + base + r];
            if (tid == 0) rid[r] = b;
            xs[r][tid] = x[(size_t)b * 256 + tid];
        }
        __syncthreads();

        float acc[ROWS];
#pragma unroll
        for (int r = 0; r < ROWS; ++r) acc[r] = bw;

        // k-loop: one coalesced W load serves ROWS rows; x via LDS broadcast float4
        for (int k0 = 0; k0 < 256; k0 += 4) {
            const float w0 = wp[(k0 + 0) * 256];
            const float w1 = wp[(k0 + 1) * 256];
            const float w2 = wp[(k0 + 2) * 256];
            const float w3 = wp[(k0 + 3) * 256];
#pragma unroll
            for (int r = 0; r < ROWS; ++r) {
                const float4 xv = *reinterpret_cast<const float4*>(&xs[r][k0]);
                acc[r] = fmaf(xv.x, w0, acc[r]);
                acc[r] = fmaf(xv.y, w1, acc[r]);
                acc[r] = fmaf(xv.z, w2, acc[r]);
                acc[r] = fmaf(xv.w, w3, acc[r]);
            }
        }

        for (int r = 0; r < nr; ++r) {
            out[(size_t)rid[r] * 256 + tid] = acc[r];
        }
        __syncthreads();   // xs/rid reused next iteration
    }
}

extern "C" void kernel_launch(void* const* d_in, const int* in_sizes, int n_in,
                              void* d_out, int out_size, void* d_ws, size_t ws_size,
                              hipStream_t stream) {
    const float* x      = (const float*)d_in[0];   // [4096, 256]
    const float* onehot = (const float*)d_in[1];   // [4096, 64]
    const float* W      = (const float*)d_in[2];   // [64, 256, 256]
    const float* Bw     = (const float*)d_in[3];   // [64, 256]
    float* out = (float*)d_out;                    // [4096, 256]

    // workspace layout: counts (64 ints) at 0, buckets (64*BCAP ints) at +1024B
    int* counts  = (int*)d_ws;
    int* buckets = (int*)((char*)d_ws + 1024);

    hipMemsetAsync(counts, 0, NBLK * sizeof(int), stream);

    dd_bucketize<<<4096 / 4, 256, 0, stream>>>(onehot, counts, buckets);

    dd_compute<<<NBLK * WPB, 256, 0, stream>>>(x, W, Bw, counts, buckets, out);
}

// Round 2
// 123.107 us; speedup vs baseline: 1.1163x; 1.1163x over previous
//
#include <hip/hip_runtime.h>

// DisjointDense: out[b] = x[b] @ W[sel[b]] + Bw[sel[b]]
// B=4096, D_IN=256, D_OUT=256, N_DISJOINT=64, all fp32.
//
// R2: bucket rows by block id, then a register-blocked batched GEMM with
//   - 1024 blocks (64 buckets x 4 row-tiles x 4 col-tiles) -> 16 waves/CU
//   - x operands via wave-uniform scalar loads (s_load_dwordx4), no LDS
//   - W via coalesced per-lane dword loads (cols across lanes)

#define NBLK 64
#define BCAP 1024

__global__ __launch_bounds__(256) void dd_bucketize(
    const float* __restrict__ onehot,   // [4096, 64]
    int* __restrict__ counts,           // [64]
    int* __restrict__ buckets)          // [64, BCAP]
{
    const int wave = threadIdx.x >> 6;
    const int lane = threadIdx.x & 63;
    const int row0 = (blockIdx.x * 4 + wave) * 4;   // 256 blocks * 4 waves * 4 rows
#pragma unroll
    for (int j = 0; j < 4; ++j) {
        const int b = row0 + j;
        const float v = onehot[(size_t)b * NBLK + lane];
        const unsigned long long m = __ballot(v > 0.5f);
        const int d = (int)__ffsll((unsigned long long)m) - 1;
        if (lane == 0) {
            int slot = atomicAdd(&counts[d], 1);
            if (slot < BCAP) buckets[d * BCAP + slot] = b;
        }
    }
}

__global__ __launch_bounds__(256) void dd_compute(
    const float* __restrict__ x,        // [4096, 256]
    const float* __restrict__ W,        // [64, 256, 256]  (d, k, col)
    const float* __restrict__ Bw,       // [64, 256]
    const int* __restrict__ counts,     // [64]
    const int* __restrict__ buckets,    // [64, BCAP]
    float* __restrict__ out)            // [4096, 256]
{
    // blockIdx: [d:6][rt:2][ct:2]
    const int d  = blockIdx.x >> 4;
    const int rt = (blockIdx.x >> 2) & 3;
    const int ct = blockIdx.x & 3;
    const int t  = threadIdx.x;
    const int c  = ct * 64 + (t & 63);   // this thread's output column
    const int rq = t >> 6;               // wave id = row quarter (4 rows each)

    const int cnt = counts[d];

    const float* Wd  = W + ((size_t)d << 16) + c;   // W[d][k][c], k-stride = 256 floats
    const float bias = Bw[d * 256 + c];

    // row-tile rt covers bucket slots [rt*16, rt*16+16) with stride 64
    for (int base = rt * 16; base < cnt; base += 64) {
        int  rid[4];
        bool valid[4];
        const float* xr[4];
#pragma unroll
        for (int j = 0; j < 4; ++j) {
            const int idx = base + rq * 4 + j;           // wave-uniform
            valid[j] = (idx < cnt);
            int r = buckets[d * BCAP + (valid[j] ? idx : (cnt - 1))];
            r = __builtin_amdgcn_readfirstlane(r);       // force SGPR -> uniform x addr
            rid[j] = r;
            xr[j]  = x + ((size_t)r << 8);
        }

        float acc[4];
#pragma unroll
        for (int j = 0; j < 4; ++j) acc[j] = bias;

        const float* wp = Wd;
#pragma unroll 2
        for (int k0 = 0; k0 < 256; k0 += 4) {
            // 4 W values for this column (coalesced across the wave's 64 lanes)
            const float w0 = wp[0 * 256];
            const float w1 = wp[1 * 256];
            const float w2 = wp[2 * 256];
            const float w3 = wp[3 * 256];
            wp += 4 * 256;
            // 4 x-row fragments, wave-uniform addresses -> scalar loads
            const float4 xv0 = *reinterpret_cast<const float4*>(xr[0] + k0);
            const float4 xv1 = *reinterpret_cast<const float4*>(xr[1] + k0);
            const float4 xv2 = *reinterpret_cast<const float4*>(xr[2] + k0);
            const float4 xv3 = *reinterpret_cast<const float4*>(xr[3] + k0);
            acc[0] = fmaf(xv0.w, w3, fmaf(xv0.z, w2, fmaf(xv0.y, w1, fmaf(xv0.x, w0, acc[0]))));
            acc[1] = fmaf(xv1.w, w3, fmaf(xv1.z, w2, fmaf(xv1.y, w1, fmaf(xv1.x, w0, acc[1]))));
            acc[2] = fmaf(xv2.w, w3, fmaf(xv2.z, w2, fmaf(xv2.y, w1, fmaf(xv2.x, w0, acc[2]))));
            acc[3] = fmaf(xv3.w, w3, fmaf(xv3.z, w2, fmaf(xv3.y, w1, fmaf(xv3.x, w0, acc[3]))));
        }

#pragma unroll
        for (int j = 0; j < 4; ++j) {
            if (valid[j]) out[((size_t)rid[j] << 8) + c] = acc[j];
        }
    }
}

extern "C" void kernel_launch(void* const* d_in, const int* in_sizes, int n_in,
                              void* d_out, int out_size, void* d_ws, size_t ws_size,
                              hipStream_t stream) {
    const float* x      = (const float*)d_in[0];   // [4096, 256]
    const float* onehot = (const float*)d_in[1];   // [4096, 64]
    const float* W      = (const float*)d_in[2];   // [64, 256, 256]
    const float* Bw     = (const float*)d_in[3];   // [64, 256]
    float* out = (float*)d_out;                    // [4096, 256]

    int* counts  = (int*)d_ws;
    int* buckets = (int*)((char*)d_ws + 1024);

    hipMemsetAsync(counts, 0, NBLK * sizeof(int), stream);
    dd_bucketize<<<256, 256, 0, stream>>>(onehot, counts, buckets);
    dd_compute<<<NBLK * 4 * 4, 256, 0, stream>>>(x, W, Bw, counts, buckets, out);
}

// Round 3
// 113.831 us; speedup vs baseline: 1.2073x; 1.0815x over previous
//
#include <hip/hip_runtime.h>

// DisjointDense: out[b] = x[b] @ W[sel[b]] + Bw[sel[b]]
// B=4096, D_IN=256, D_OUT=256, N_DISJOINT=64, all fp32.
//
// R3:
//  - bucketize: LDS-aggregated histogram (16 global atomics/counter, counters
//    padded to 1/cache-line) -- kills the cross-XCD atomic serialization that
//    ate ~60us in R1/R2.
//  - compute: 4096 independent waves (64 buckets x 16 row-quads x 4 col-groups),
//    no idle k-loops on bucket tails, W prefetched 8-deep with ping-pong
//    registers to cover L2 latency at 4 waves/SIMD.

#define NBLK 64
#define BCAP 1024
#define CPAD 16   // counter padding: 16 ints = 64B = 1 cache line per counter

__global__ __launch_bounds__(256) void dd_bucketize(
    const float* __restrict__ onehot,   // [4096, 64]
    int* __restrict__ counts,           // [64*CPAD], zeroed
    int* __restrict__ buckets)          // [64, BCAP]
{
    __shared__ int lhist[NBLK];
    __shared__ int lbase[NBLK];
    const int tid = threadIdx.x;
    if (tid < NBLK) lhist[tid] = 0;
    __syncthreads();

    const int b = blockIdx.x * 256 + tid;          // 16 blocks x 256 rows
    const float4* rp = (const float4*)(onehot + (size_t)b * NBLK);
    float fd = 0.f;
#pragma unroll
    for (int k = 0; k < 16; ++k) {
        const float4 v = rp[k];
        fd += v.x * (4 * k + 0) + v.y * (4 * k + 1) + v.z * (4 * k + 2) + v.w * (4 * k + 3);
    }
    const int d = (int)(fd + 0.5f);                // exact: row is one-hot
    const int slot = atomicAdd(&lhist[d], 1);      // LDS atomic (fast)
    __syncthreads();
    if (tid < NBLK) lbase[tid] = atomicAdd(&counts[tid * CPAD], lhist[tid]);
    __syncthreads();
    buckets[d * BCAP + lbase[d] + slot] = b;
}

__global__ __launch_bounds__(256) void dd_compute(
    const float* __restrict__ x,        // [4096, 256]
    const float* __restrict__ W,        // [64, 256, 256]  (d, k, col)
    const float* __restrict__ Bw,       // [64, 256]
    const int* __restrict__ counts,     // [64*CPAD]
    const int* __restrict__ buckets,    // [64, BCAP]
    float* __restrict__ out)            // [4096, 256]
{
    const int t    = threadIdx.x;
    const int lane = t & 63;
    const int g    = blockIdx.x * 4 + (t >> 6);    // global wave id, 0..4095
    const int d    = g >> 6;
    const int sub  = g & 63;
    const int q0   = sub >> 2;                     // row-quad 0..15
    const int ct   = sub & 3;                      // col-group
    const int c    = ct * 64 + lane;               // output column

    const int cnt = counts[d * CPAD];
    const float* Wd  = W + ((size_t)d << 16) + c;  // W[d][k][c], k-stride 256
    const float bias = Bw[d * 256 + c];

    for (int q = q0; q * 4 < cnt; q += 16) {       // waves past cnt exit instantly
        const int base = q * 4;
        int  rid[4];
        bool valid[4];
        const float* xr[4];
#pragma unroll
        for (int j = 0; j < 4; ++j) {
            const int idx = base + j;
            valid[j] = (idx < cnt);
            int r = buckets[d * BCAP + (valid[j] ? idx : cnt - 1)];
            r = __builtin_amdgcn_readfirstlane(r); // uniform -> scalar x addressing
            rid[j] = r;
            xr[j]  = x + ((size_t)r << 8);
        }

        float acc[4];
#pragma unroll
        for (int j = 0; j < 4; ++j) acc[j] = bias;

        float wa[8], wb[8];
#pragma unroll
        for (int i = 0; i < 8; ++i) wa[i] = Wd[i * 256];

#pragma unroll 1
        for (int k0 = 0; k0 < 256; k0 += 16) {
            // prefetch next 8 W values while computing with wa (k0..k0+7)
#pragma unroll
            for (int i = 0; i < 8; ++i) wb[i] = Wd[((k0 + 8 + i) & 255) * 256];
#pragma unroll
            for (int j = 0; j < 4; ++j) {
                const float4 xa = *(const float4*)(xr[j] + k0);
                const float4 xc = *(const float4*)(xr[j] + k0 + 4);
                acc[j] = fmaf(xa.x, wa[0], acc[j]);
                acc[j] = fmaf(xa.y, wa[1], acc[j]);
                acc[j] = fmaf(xa.z, wa[2], acc[j]);
                acc[j] = fmaf(xa.w, wa[3], acc[j]);
                acc[j] = fmaf(xc.x, wa[4], acc[j]);
                acc[j] = fmaf(xc.y, wa[5], acc[j]);
                acc[j] = fmaf(xc.z, wa[6], acc[j]);
                acc[j] = fmaf(xc.w, wa[7], acc[j]);
            }
            // prefetch following 8 while computing with wb (k0+8..k0+15)
#pragma unroll
            for (int i = 0; i < 8; ++i) wa[i] = Wd[((k0 + 16 + i) & 255) * 256];
#pragma unroll
            for (int j = 0; j < 4; ++j) {
                const float4 xa = *(const float4*)(xr[j] + k0 + 8);
                const float4 xc = *(const float4*)(xr[j] + k0 + 12);
                acc[j] = fmaf(xa.x, wb[0], acc[j]);
                acc[j] = fmaf(xa.y, wb[1], acc[j]);
                acc[j] = fmaf(xa.z, wb[2], acc[j]);
                acc[j] = fmaf(xa.w, wb[3], acc[j]);
                acc[j] = fmaf(xc.x, wb[4], acc[j]);
                acc[j] = fmaf(xc.y, wb[5], acc[j]);
                acc[j] = fmaf(xc.z, wb[6], acc[j]);
                acc[j] = fmaf(xc.w, wb[7], acc[j]);
            }
        }

#pragma unroll
        for (int j = 0; j < 4; ++j) {
            if (valid[j]) out[((size_t)rid[j] << 8) + c] = acc[j];
        }
    }
}

extern "C" void kernel_launch(void* const* d_in, const int* in_sizes, int n_in,
                              void* d_out, int out_size, void* d_ws, size_t ws_size,
                              hipStream_t stream) {
    const float* x      = (const float*)d_in[0];   // [4096, 256]
    const float* onehot = (const float*)d_in[1];   // [4096, 64]
    const float* W      = (const float*)d_in[2];   // [64, 256, 256]
    const float* Bw     = (const float*)d_in[3];   // [64, 256]
    float* out = (float*)d_out;                    // [4096, 256]

    int* counts  = (int*)d_ws;                             // 64*CPAD ints (4 KB)
    int* buckets = (int*)((char*)d_ws + NBLK * CPAD * 4);  // 64*BCAP ints (256 KB)

    hipMemsetAsync(counts, 0, NBLK * CPAD * sizeof(int), stream);
    dd_bucketize<<<16, 256, 0, stream>>>(onehot, counts, buckets);
    dd_compute<<<NBLK * 16, 256, 0, stream>>>(x, W, Bw, counts, buckets, out);
}